// Round 3
// baseline (270.299 us; speedup 1.0000x reference)
//
#include <hip/hip_runtime.h>
#include <hip/hip_cooperative_groups.h>
#include <math.h>

namespace cg = cooperative_groups;

#define BB 16
#define NN 256
#define DD 32

// Single cooperative kernel. Grid = 512 blocks x 256 threads (2 blocks/CU on
// 256 CUs -> co-residency guaranteed: ~2KB LDS, 4 waves/block).
//
// Phase A: block g handles 8 nodes (g0 = g*8).
//   u[n,:] = x[n,:] @ W_out[0:32,:]          (sender half)
//   v[n,:] = x[n,:] @ W_out[32:64,:] + b_out (receiver half)
//   Writes uT/xT in chunk-transposed layout [b][q][n] (float4 granule) so
//   phase B's per-column reads are coalesced. v stays row-major (broadcast).
// Phase B: block = (b, rowgroup of 8). Thread t = column j. m kept in regs.
// Phase C: per-block redundant batch-stats reduction + normalize + store.
//   LayerNorm algebra: with m2[i,j] = m[i,j] + rowmean_i,
//     sum(m2) = 2*sum(m);  sum(m2^2) = sum(m^2) + 3*N*sum_i(rowmean_i^2)
__global__ __launch_bounds__(256) void fused_kernel(
    const float* __restrict__ x,
    const float* __restrict__ W_out, const float* __restrict__ b_out,
    const float* __restrict__ W_cat, const float* __restrict__ b_cat,
    const float* __restrict__ W_f1,  const float* __restrict__ b_f1,
    const float* __restrict__ W_f2,  const float* __restrict__ b_f2,
    float* __restrict__ uT, float* __restrict__ xT, float* __restrict__ v,
    float* __restrict__ rowsum, float* __restrict__ rowsq,
    float* __restrict__ out)
{
    cg::grid_group grid = cg::this_grid();
    __shared__ float lxA[256];
    __shared__ float red0[8][4], red1[8][4];
    __shared__ float sred[12];
    __shared__ float stat[2];

    const int t   = threadIdx.x;
    const int blk = blockIdx.x;
    const int b   = blk >> 5;           // 32 blocks per batch

    // ---------------- Phase A: u/v transform + transpose ----------------
    {
        int g0 = blk * 8;               // first global node of this block
        lxA[t] = x[g0 * DD + t];        // 8 nodes x 32 dims, coalesced
        __syncthreads();
        int nl = t >> 5, d = t & 31;
        int nb = (g0 + nl) & (NN - 1);  // node index within batch
        float su = 0.f, sv = 0.f;
#pragma unroll
        for (int k = 0; k < DD; ++k) {
            float xv = lxA[nl * DD + k];
            su += xv * W_out[k * DD + d];
            sv += xv * W_out[(k + DD) * DD + d];
        }
        int idxT = ((b * 8 + (d >> 2)) * NN + nb) * 4 + (d & 3);
        uT[idxT] = su;
        xT[idxT] = lxA[nl * DD + d];
        v[(size_t)(g0 + nl) * DD + d] = sv + b_out[d];
    }
    __threadfence();
    grid.sync();
    __threadfence();

    // ---------------- Phase B: pairs, m in registers ----------------
    const int i0 = (blk & 31) * 8;      // this block's 8 rows
    const float4* uT4 = (const float4*)uT;
    const float4* xT4 = (const float4*)xT;

    float4 uj[8], xj[8];
#pragma unroll
    for (int q = 0; q < 8; ++q) {       // coalesced: lanes = consecutive cols
        uj[q] = uT4[(b * 8 + q) * NN + t];
        xj[q] = xT4[(b * 8 + q) * NN + t];
    }

    const float4* Wc4 = (const float4*)W_cat;
    float4 wc[8];
#pragma unroll
    for (int q = 0; q < 8; ++q) wc[q] = Wc4[q];
    float f1a[8], f1b[8], fb1[8], f2w[8];
#pragma unroll
    for (int k = 0; k < 8; ++k) {
        f1a[k] = W_f1[k];       // W_f1[0,k]
        f1b[k] = W_f1[8 + k];   // W_f1[1,k]
        fb1[k] = b_f1[k];
        f2w[k] = W_f2[k];
    }
    const float bcat = b_cat[0], bf2 = b_f2[0];

    float mreg[8];
    const int lane = t & 63, wv = t >> 6;
#pragma unroll
    for (int r = 0; r < 8; ++r) {
        int i = i0 + r;
        const float4* vi4 = (const float4*)(v + ((size_t)b * NN + i) * DD);
        const float4* xi4 = (const float4*)(x + ((size_t)b * NN + i) * DD);
        float e = 0.f, mp = 0.f;
#pragma unroll
        for (int c = 0; c < 8; ++c) {
            float4 vi = vi4[c];         // wave-uniform
            float4 xi = xi4[c];         // wave-uniform
            float4 uu = uj[c], xx = xj[c];
            e += fmaxf(uu.x + vi.x, 0.f) * wc[c].x;
            e += fmaxf(uu.y + vi.y, 0.f) * wc[c].y;
            e += fmaxf(uu.z + vi.z, 0.f) * wc[c].z;
            e += fmaxf(uu.w + vi.w, 0.f) * wc[c].w;
            mp += xx.x * xi.x + xx.y * xi.y + xx.z * xi.z + xx.w * xi.w;
        }
        e = fmaxf(e + bcat, 0.f);
        float mlin = (t == i) ? 0.f : e;
        float s = bf2;
#pragma unroll
        for (int k = 0; k < 8; ++k)
            s += fmaxf(mlin * f1a[k] + mp * f1b[k] + fb1[k], 0.f) * f2w[k];
        float w = 1.f / (1.f + expf(-s));
        float m = w * mlin + (1.f - w) * mp;
        mreg[r] = m;

        float sm = m, sq = m * m;       // deterministic wave-tree reduce
#pragma unroll
        for (int off = 32; off; off >>= 1) {
            sm += __shfl_down(sm, off);
            sq += __shfl_down(sq, off);
        }
        if (lane == 0) { red0[r][wv] = sm; red1[r][wv] = sq; }
    }
    __syncthreads();
    if (t < 8) {
        rowsum[b * NN + i0 + t] = red0[t][0] + red0[t][1] + red0[t][2] + red0[t][3];
        rowsq [b * NN + i0 + t] = red1[t][0] + red1[t][1] + red1[t][2] + red1[t][3];
    }
    __threadfence();
    grid.sync();
    __threadfence();

    // ---------------- Phase C: batch stats + normalize ----------------
    {
        float rs = rowsum[b * NN + t];
        float rq = rowsq [b * NN + t];
        float rr = rs * (1.f / NN);
        float sM = rs, sQ = rq, sR = rr * rr;
#pragma unroll
        for (int off = 32; off; off >>= 1) {
            sM += __shfl_down(sM, off);
            sQ += __shfl_down(sQ, off);
            sR += __shfl_down(sR, off);
        }
        if (lane == 0) { sred[wv] = sM; sred[4 + wv] = sQ; sred[8 + wv] = sR; }
        __syncthreads();
        if (t == 0) {
            float sumM  = sred[0] + sred[1] + sred[2] + sred[3];
            float sumQ  = sred[4] + sred[5] + sred[6] + sred[7];
            float sumR2 = sred[8] + sred[9] + sred[10] + sred[11];
            const float inv = 1.f / ((float)NN * (float)NN);
            float mu  = 2.f * sumM * inv;
            float ex2 = (sumQ + 3.f * (float)NN * sumR2) * inv;
            stat[0] = mu;
            stat[1] = rsqrtf(ex2 - mu * mu + 1e-5f);
        }
        __syncthreads();
        float mu = stat[0], rstd = stat[1];
#pragma unroll
        for (int r = 0; r < 8; ++r) {
            int i = i0 + r;
            float ri = rowsum[b * NN + i] * (1.f / NN);   // wave-uniform
            out[((size_t)b * NN + i) * NN + t] = (mreg[r] + ri - mu) * rstd;
        }
    }
}

extern "C" void kernel_launch(void* const* d_in, const int* in_sizes, int n_in,
                              void* d_out, int out_size, void* d_ws, size_t ws_size,
                              hipStream_t stream)
{
    const float* x     = (const float*)d_in[0];
    const float* W_out = (const float*)d_in[1];
    const float* b_out = (const float*)d_in[2];
    const float* W_cat = (const float*)d_in[3];
    const float* b_cat = (const float*)d_in[4];
    const float* W_f1  = (const float*)d_in[5];
    const float* b_f1  = (const float*)d_in[6];
    const float* W_f2  = (const float*)d_in[7];
    const float* b_f2  = (const float*)d_in[8];

    float* ws     = (float*)d_ws;
    float* uT     = ws;                         // BB*8*NN*4 = 131072
    float* xT     = uT + BB * 8 * NN * 4;       // 131072
    float* v      = xT + BB * 8 * NN * 4;       // BB*NN*DD = 131072
    float* rowsum = v + BB * NN * DD;           // BB*NN
    float* rowsq  = rowsum + BB * NN;           // BB*NN
    float* outp   = (float*)d_out;

    void* args[] = {
        (void*)&x, (void*)&W_out, (void*)&b_out, (void*)&W_cat, (void*)&b_cat,
        (void*)&W_f1, (void*)&b_f1, (void*)&W_f2, (void*)&b_f2,
        (void*)&uT, (void*)&xT, (void*)&v, (void*)&rowsum, (void*)&rowsq,
        (void*)&outp
    };
    hipLaunchCooperativeKernel((const void*)fused_kernel,
                               dim3(BB * (NN / 8)), dim3(256),
                               args, 0, stream);
}

// Round 4
// 25.419 us; speedup vs baseline: 10.6339x; 10.6339x over previous
//
#include <hip/hip_runtime.h>
#include <math.h>

#define BB 16
#define NN 256
#define DD 32

// ---------------------------------------------------------------------------
// K1: per-node transform, outputs in chunk-transposed layout:
//   uT[((b*8+q)*NN + n)*4 + c] = (x[b,n] @ W_out[0:32])[4q+c]
//   vT[...]                    = (x[b,n] @ W_out[32:64] + b_out)[4q+c]
//   xT[...]                    = x[b,n][4q+c]
// so that K2's per-lane column reads (lane j -> node j) are coalesced float4
// loads and row reads (node i) are wave-uniform float4 loads.
// 8 nodes per 256-thread block; thread = (node_in_block, d).
// ---------------------------------------------------------------------------
__global__ __launch_bounds__(256) void uvT_kernel(
    const float* __restrict__ x,
    const float* __restrict__ W_out,
    const float* __restrict__ b_out,
    float* __restrict__ uT, float* __restrict__ xT, float* __restrict__ vT)
{
    __shared__ float lxA[256];
    int t = threadIdx.x;
    int g0 = blockIdx.x * 8;            // first global node (b*NN+n)
    lxA[t] = x[(size_t)g0 * DD + t];    // coalesced: 8 nodes x 32 dims
    __syncthreads();

    int nl = t >> 5, d = t & 31;
    int b  = (g0 + nl) >> 8;
    int n  = (g0 + nl) & 255;
    float su = 0.f, sv = 0.f;
#pragma unroll
    for (int k = 0; k < DD; ++k) {
        float xv = lxA[nl * DD + k];    // LDS broadcast across d-lanes
        su += xv * W_out[k * DD + d];          // coalesced, L1-hot
        sv += xv * W_out[(k + DD) * DD + d];
    }
    int idxT = ((b * 8 + (d >> 2)) * NN + n) * 4 + (d & 3);
    uT[idxT] = su;
    vT[idxT] = sv + b_out[d];
    xT[idxT] = lxA[nl * DD + d];
}

// ---------------------------------------------------------------------------
// K2: pair kernel, no LDS staging. Block = (b, rowgroup of 8 rows), 256 thr.
// Thread = column j. Per row i:
//   h = relu(u_j + v_i); e = relu(h.W_cat + b_cat); mlin = (i==j)?0:e
//   mprod = x_i . x_j
//   w = sigmoid(relu([mlin,mprod]@W_f1+b_f1)@W_f2+b_f2)
//   m = w*mlin + (1-w)*mprod
// Column data (u_j, x_j): coalesced float4 loads from uT/xT.
// Row data (v_i, x_i): wave-uniform float4 loads (single line, broadcast).
// Writes m (coalesced) + per-row sum/sumsq (deterministic shuffle tree).
// ---------------------------------------------------------------------------
__global__ __launch_bounds__(256) void pair_kernel(
    const float* __restrict__ uT, const float* __restrict__ xT,
    const float* __restrict__ vT,
    const float* __restrict__ W_cat, const float* __restrict__ b_cat,
    const float* __restrict__ W_f1,  const float* __restrict__ b_f1,
    const float* __restrict__ W_f2,  const float* __restrict__ b_f2,
    float* __restrict__ m_out,
    float* __restrict__ rowsum_out, float* __restrict__ rowsq_out)
{
    __shared__ float red0[8][4], red1[8][4];

    const int t  = threadIdx.x;          // column j
    const int b  = blockIdx.x >> 5;
    const int i0 = (blockIdx.x & 31) * 8;

    const float4* uT4 = (const float4*)uT;
    const float4* xT4 = (const float4*)xT;
    const float4* vT4 = (const float4*)vT;

    float4 uj[8], xj[8];
#pragma unroll
    for (int q = 0; q < 8; ++q) {        // coalesced: lanes = consecutive nodes
        uj[q] = uT4[(b * 8 + q) * NN + t];
        xj[q] = xT4[(b * 8 + q) * NN + t];
    }

    const float4* Wc4 = (const float4*)W_cat;
    float4 wc[8];
#pragma unroll
    for (int q = 0; q < 8; ++q) wc[q] = Wc4[q];
    float f1a[8], f1b[8], fb1[8], f2w[8];
#pragma unroll
    for (int k = 0; k < 8; ++k) {
        f1a[k] = W_f1[k];        // W_f1[0,k]
        f1b[k] = W_f1[8 + k];    // W_f1[1,k]
        fb1[k] = b_f1[k];
        f2w[k] = W_f2[k];
    }
    const float bcat = b_cat[0], bf2 = b_f2[0];

    const int lane = t & 63, wv = t >> 6;
    float mreg[8];
#pragma unroll
    for (int r = 0; r < 8; ++r) {
        int i = i0 + r;
        float e = 0.f, mp = 0.f;
#pragma unroll
        for (int q = 0; q < 8; ++q) {
            float4 vi = vT4[(b * 8 + q) * NN + i];   // wave-uniform
            float4 xi = xT4[(b * 8 + q) * NN + i];   // wave-uniform
            float4 uu = uj[q], xx = xj[q];
            e += fmaxf(uu.x + vi.x, 0.f) * wc[q].x;
            e += fmaxf(uu.y + vi.y, 0.f) * wc[q].y;
            e += fmaxf(uu.z + vi.z, 0.f) * wc[q].z;
            e += fmaxf(uu.w + vi.w, 0.f) * wc[q].w;
            mp += xx.x * xi.x + xx.y * xi.y + xx.z * xi.z + xx.w * xi.w;
        }
        e = fmaxf(e + bcat, 0.f);
        float mlin = (t == i) ? 0.f : e;
        float s = bf2;
#pragma unroll
        for (int k = 0; k < 8; ++k)
            s += fmaxf(mlin * f1a[k] + mp * f1b[k] + fb1[k], 0.f) * f2w[k];
        float w = 1.f / (1.f + expf(-s));
        float m = w * mlin + (1.f - w) * mp;
        mreg[r] = m;

        float sm = m, sq = m * m;        // deterministic wave-tree reduce
#pragma unroll
        for (int off = 32; off; off >>= 1) {
            sm += __shfl_down(sm, off);
            sq += __shfl_down(sq, off);
        }
        if (lane == 0) { red0[r][wv] = sm; red1[r][wv] = sq; }
    }

#pragma unroll
    for (int r = 0; r < 8; ++r)          // coalesced m store
        m_out[((size_t)b * NN + i0 + r) * NN + t] = mreg[r];

    __syncthreads();
    if (t < 8) {
        rowsum_out[b * NN + i0 + t] = red0[t][0] + red0[t][1] + red0[t][2] + red0[t][3];
        rowsq_out [b * NN + i0 + t] = red1[t][0] + red1[t][1] + red1[t][2] + red1[t][3];
    }
}

// ---------------------------------------------------------------------------
// K3: fused stats + finalize. Block = (b, 8 rows), 256 threads.
// Redundant per-block reduction of the batch's 256 rowsum/rowsq (2KB, L2-hot)
// via the m2 algebra:
//   sum(m2) = 2*sum(m);  sum(m2^2) = sum(m^2) + 3*N*sum_i(rowmean_i^2)
// then out[b,i,j] = (m[b,i,j] + rowmean_i - mu) * rstd.
// ---------------------------------------------------------------------------
__global__ __launch_bounds__(256) void final_kernel(
    const float* __restrict__ m_in,
    const float* __restrict__ rowsum, const float* __restrict__ rowsq,
    float* __restrict__ out)
{
    __shared__ float sred[12];
    __shared__ float stat[2];
    int t  = threadIdx.x;
    int b  = blockIdx.x >> 5;
    int r0 = (blockIdx.x & 31) * 8;

    float rs = rowsum[b * NN + t];
    float rq = rowsq [b * NN + t];
    float rr = rs * (1.f / NN);
    float sM = rs, sQ = rq, sR = rr * rr;
#pragma unroll
    for (int off = 32; off; off >>= 1) {
        sM += __shfl_down(sM, off);
        sQ += __shfl_down(sQ, off);
        sR += __shfl_down(sR, off);
    }
    int wave = t >> 6;
    if ((t & 63) == 0) { sred[wave] = sM; sred[4 + wave] = sQ; sred[8 + wave] = sR; }
    __syncthreads();
    if (t == 0) {
        float sumM  = sred[0] + sred[1] + sred[2] + sred[3];
        float sumQ  = sred[4] + sred[5] + sred[6] + sred[7];
        float sumR2 = sred[8] + sred[9] + sred[10] + sred[11];
        const float inv = 1.f / ((float)NN * (float)NN);
        float mu  = 2.f * sumM * inv;
        float ex2 = (sumQ + 3.f * (float)NN * sumR2) * inv;
        stat[0] = mu;
        stat[1] = rsqrtf(ex2 - mu * mu + 1e-5f);
    }
    __syncthreads();
    float mu = stat[0], rstd = stat[1];
#pragma unroll
    for (int r = 0; r < 8; ++r) {
        int i = r0 + r;
        size_t base = ((size_t)b * NN + i) * NN;
        float ri = rowsum[b * NN + i] * (1.f / NN);   // uniform, L1-hot
        out[base + t] = (m_in[base + t] + ri - mu) * rstd;
    }
}

extern "C" void kernel_launch(void* const* d_in, const int* in_sizes, int n_in,
                              void* d_out, int out_size, void* d_ws, size_t ws_size,
                              hipStream_t stream)
{
    const float* x     = (const float*)d_in[0];
    const float* W_out = (const float*)d_in[1];
    const float* b_out = (const float*)d_in[2];
    const float* W_cat = (const float*)d_in[3];
    const float* b_cat = (const float*)d_in[4];
    const float* W_f1  = (const float*)d_in[5];
    const float* b_f1  = (const float*)d_in[6];
    const float* W_f2  = (const float*)d_in[7];
    const float* b_f2  = (const float*)d_in[8];

    float* ws     = (float*)d_ws;
    float* uT     = ws;                         // BB*NN*DD
    float* xT     = uT + BB * NN * DD;          // BB*NN*DD
    float* vT     = xT + BB * NN * DD;          // BB*NN*DD
    float* m      = vT + BB * NN * DD;          // BB*NN*NN
    float* rowsum = m + (size_t)BB * NN * NN;   // BB*NN
    float* rowsq  = rowsum + BB * NN;           // BB*NN

    uvT_kernel <<<BB * NN / 8, 256, 0, stream>>>(x, W_out, b_out, uT, xT, vT);
    pair_kernel<<<BB * (NN / 8), 256, 0, stream>>>(uT, xT, vT, W_cat, b_cat,
                                                   W_f1, b_f1, W_f2, b_f2,
                                                   m, rowsum, rowsq);
    final_kernel<<<BB * (NN / 8), 256, 0, stream>>>(m, rowsum, rowsq, (float*)d_out);
}